// Round 10
// baseline (335.865 us; speedup 1.0000x reference)
//
#include <hip/hip_runtime.h>

// Problem: T=128, B=64, STATE=32, LATENT=16, AC=8, MS=8, SE=64, AE=16, H=64, OUT=18
// d_out layout: [0] = kl_loss, [1 .. 8192] = recon_loss[s*64+b]  (out_size = 8193, f32)
// d_ws layout:  [0, 6291456)  xi  (T,B,192) f32   = embed@Wi + bi  ([0:64)=ir,[64:128)=iz,[128:192)=i_n)
//               [6291456, 8388608) hid0 (T,B,64) f32
//               [8388608, +4) work-steal counter

#define XI_OFF   0
#define HID_OFF  6291456
#define CTR_OFF  8388608

typedef float f32x16 __attribute__((ext_vector_type(16)));
typedef float f32x4  __attribute__((ext_vector_type(4)));
typedef __fp16 fp16x4 __attribute__((ext_vector_type(4)));

#if defined(__HIP_DEVICE_COMPILE__)
#if __has_builtin(__builtin_amdgcn_mfma_f32_16x16x16f16)
#define MFMA16(a, b, c) __builtin_amdgcn_mfma_f32_16x16x16f16((a), (b), (c), 0, 0, 0)
#else
#define MFMA16(a, b, c) __builtin_amdgcn_mfma_f32_16x16x16_f16((a), (b), (c), 0, 0, 0)
#endif
#else
#define MFMA16(a, b, c) (c)   /* host pass: type-check only, never executed */
#endif

// ---------------- Fused precompute (blocks 0..255) + KL (blocks 256..319) ----------------
__global__ __launch_bounds__(256, 1) void precompute_kernel(
    const float* __restrict__ state, const float* __restrict__ ac, const float* __restrict__ ms,
    const float* __restrict__ Wst, const float* __restrict__ bst,
    const float* __restrict__ Wac, const float* __restrict__ bac,
    const float* __restrict__ Wem, const float* __restrict__ bem,
    const float* __restrict__ Whd, const float* __restrict__ bhd,
    const float* __restrict__ Wi,  const float* __restrict__ bi,
    const float* __restrict__ lm, const float* __restrict__ lv,
    const float* __restrict__ lmt, const float* __restrict__ lvt,
    float* __restrict__ xi, float* __restrict__ hid0, float* __restrict__ out) {
  __shared__ float sWst[32 * 64];
  __shared__ float sWem[80 * 64];
  __shared__ float sWhd[24 * 64];
  __shared__ float sWac[8 * 16];
  __shared__ float sb[208];
  __shared__ float sin_[4][48];
  __shared__ float sse[4][80];
  __shared__ float semb[4][64];
  __shared__ float ps[4];
  int tid = threadIdx.x, lane = tid & 63, w = tid >> 6;

  if (blockIdx.x >= 256) {
    float total = 0.f;
    for (int it = 0; it < 16; ++it) {
      int idx = ((int)blockIdx.x - 256) * 256 + tid + it * 16384;
      int g = idx & 31;
      int pair = idx >> 5;
      const float* M = (g < 16) ? lm : lmt;
      const float* V = (g < 16) ? lv : lvt;
      int cur = pair * 16 + (g & 15);
      float mu = M[cur], lE = V[cur];
      float m = 0.f, lS = 0.f;
      if (pair >= 64) { m = M[cur - 1024]; lS = V[cur - 1024]; }
      float d = m - mu;
      total += 0.5f * (lS - lE - 1.f + __expf(lE - lS) + d * d * __expf(-lS));
    }
    #pragma unroll
    for (int off = 32; off; off >>= 1) total += __shfl_xor(total, off);
    if (lane == 0) ps[w] = total;
    __syncthreads();
    if (tid == 0) atomicAdd(out, ps[0] + ps[1] + ps[2] + ps[3]);
    return;
  }

  f32x16 wi0[4], wi1[4], wi2[4];
  #pragma unroll
  for (int k = 0; k < 64; ++k) {
    wi0[k >> 4][k & 15] = Wi[k * 192 + lane];
    wi1[k >> 4][k & 15] = Wi[k * 192 + 64 + lane];
    wi2[k >> 4][k & 15] = Wi[k * 192 + 128 + lane];
  }
  for (int i = tid; i < 32 * 64; i += 256) sWst[i] = Wst[i];
  for (int i = tid; i < 80 * 64; i += 256) sWem[i] = Wem[i];
  for (int i = tid; i < 24 * 64; i += 256) sWhd[i] = Whd[i];
  for (int i = tid; i < 8 * 16; i += 256) sWac[i] = Wac[i];
  if (tid < 64) sb[tid] = bst[tid];
  if (tid < 16) sb[64 + tid] = bac[tid];
  if (tid < 64) sb[80 + tid] = bem[tid];
  if (tid < 64) sb[144 + tid] = bhd[tid];
  float bi0 = bi[lane], bi1 = bi[64 + lane], bi2 = bi[128 + lane];
  __syncthreads();
  for (int cnt = 0; cnt < 8; ++cnt) {
    int pair = blockIdx.x * 32 + w * 8 + cnt;
    if (lane < 32)      sin_[w][lane] = state[pair * 32 + lane];
    else if (lane < 40) sin_[w][lane] = ac[pair * 8 + (lane - 32)];
    else if (lane < 48) sin_[w][lane] = ms[pair * 8 + (lane - 40)];
    __syncthreads();
    float se = sb[lane];
    #pragma unroll
    for (int k = 0; k < 32; ++k) se += sin_[w][k] * sWst[k * 64 + lane];
    se = fmaxf(se, 0.f);
    float ae = 0.f;
    if (lane < 16) {
      ae = sb[64 + lane];
      #pragma unroll
      for (int k = 0; k < 8; ++k) ae += sin_[w][32 + k] * sWac[k * 16 + lane];
      ae = fmaxf(ae, 0.f);
    }
    __syncthreads();
    sse[w][lane] = se;
    if (lane < 16) sse[w][64 + lane] = ae;
    __syncthreads();
    float em = sb[80 + lane];
    #pragma unroll
    for (int k = 0; k < 80; ++k) em += sse[w][k] * sWem[k * 64 + lane];
    float hd = sb[144 + lane];
    #pragma unroll
    for (int k = 0; k < 16; ++k) hd += sse[w][64 + k] * sWhd[k * 64 + lane];
    #pragma unroll
    for (int k = 0; k < 8; ++k) hd += sin_[w][40 + k] * sWhd[(16 + k) * 64 + lane];
    hid0[pair * 64 + lane] = hd;
    semb[w][lane] = em;
    __syncthreads();
    float x0 = bi0, x1 = bi1, x2 = bi2;
    #pragma unroll
    for (int k = 0; k < 64; ++k) {
      float e = semb[w][k];
      x0 += e * wi0[k >> 4][k & 15];
      x1 += e * wi1[k >> 4][k & 15];
      x2 += e * wi2[k >> 4][k & 15];
    }
    float* xo = xi + pair * 192;
    xo[lane] = x0; xo[64 + lane] = x1; xo[128 + lane] = x2;
    __syncthreads();
  }
}

// ---------------- Rollout: 8 sequences per wave via MFMA ----------------
// G^T(192x16) = W^T @ H^T with v_mfma_f32_16x16x16_f16.
// Layouts (classic CDNA): A: m=lane&15, k=4*(lane>>4)+j;  B: n=lane&15, same k;
// C/D: col(n)=lane&15, row(m)=4*(lane>>4)+r.
// Slots = B-cols 0..7 (cols 8..15 read zeroed LDS rows, outputs ignored).
// h state in C-layout f32 regs; LDS bounce hbuf[16][72]f16 forms B-fragments.
__global__ __launch_bounds__(64, 2) void rollout_kernel(
    const float* __restrict__ xi, const float* __restrict__ hid0,
    const float* __restrict__ dones, const int* __restrict__ actions,
    const float* __restrict__ Whrz, const float* __restrict__ Whn,
    const float* __restrict__ bhn, const float* __restrict__ Wout,
    const float* __restrict__ bout, float* __restrict__ out,
    unsigned int* __restrict__ ctr) {
  __shared__ __attribute__((aligned(16))) __fp16 hbuf[16 * 72];  // [seq][72], stride 144B
  __shared__ float sbh[64];   // bhn
  __shared__ float sbo[20];   // bout + 2 zeros
  int lane = threadIdx.x;
  int g = lane >> 4, col = lane & 15, slot = col & 7;

  // ---- weights as A-fragments (MFMA reads VGPR/AGPR natively) ----
  fp16x4 aW[12][4];           // gates: W_combined^T, 96 regs
  #pragma unroll
  for (int mt = 0; mt < 12; ++mt)
    #pragma unroll
    for (int kt = 0; kt < 4; ++kt)
      #pragma unroll
      for (int j = 0; j < 4; ++j) {
        int kk = kt * 16 + g * 4 + j;
        int m = mt * 16 + col;
        float v = (m < 128) ? Whrz[kk * 128 + m] : Whn[kk * 64 + (m - 128)];
        aW[mt][kt][j] = (__fp16)v;
      }
  fp16x4 aO[2][4];            // logits: Wout^T (cls pad to 32), 16 regs
  #pragma unroll
  for (int mt = 0; mt < 2; ++mt)
    #pragma unroll
    for (int kt = 0; kt < 4; ++kt)
      #pragma unroll
      for (int j = 0; j < 4; ++j) {
        int kk = kt * 16 + g * 4 + j;
        int cls = mt * 16 + col;
        aO[mt][kt][j] = (__fp16)((cls < 18) ? Wout[kk * 18 + cls] : 0.f);
      }
  for (int i = lane; i < 16 * 72; i += 64) hbuf[i] = (__fp16)0.f;
  sbh[lane] = bhn[lane];
  if (lane < 18) sbo[lane] = bout[lane];
  if (lane < 2)  sbo[18 + lane] = 0.f;
  __syncthreads();

  // ---- initial pop: 8 consecutive sequences (same t) ----
  int base = 0;
  if (lane == 0) base = (int)atomicAdd(ctr, 8u);
  base = __shfl(base, 0);
  int idx = base + slot;
  bool live = idx < 8192;
  int u = idx >> 6, b = idx & 63, scnt = 0;
  bool fresh = true;
  int pair = u * 64 + b;
  // prefetch step inputs (all lanes mirror slot col&7; no masking on loads)
  float d = dones[pair];
  int act = actions[pair];
  f32x4 acc[12], xvn[4];
  #pragma unroll
  for (int mt = 0; mt < 8; ++mt) acc[mt] = *(const f32x4*)(xi + pair * 192 + mt * 16 + g * 4);
  #pragma unroll
  for (int t = 0; t < 4; ++t) xvn[t] = *(const f32x4*)(xi + pair * 192 + 128 + t * 16 + g * 4);

  f32x4 h4[4] = {f32x4{0,0,0,0}, f32x4{0,0,0,0}, f32x4{0,0,0,0}, f32x4{0,0,0,0}};

  while (__ballot(live)) {
    // ---- episode reset / fresh start: h = hid0[pair] ----
    if (d > 0.f || fresh) {
      #pragma unroll
      for (int t = 0; t < 4; ++t) h4[t] = *(const f32x4*)(hid0 + pair * 64 + t * 16 + g * 4);
      fresh = false;
      if (col < 8) {
        #pragma unroll
        for (int t = 0; t < 4; ++t) {
          fp16x4 hw; hw[0]=(__fp16)h4[t][0]; hw[1]=(__fp16)h4[t][1]; hw[2]=(__fp16)h4[t][2]; hw[3]=(__fp16)h4[t][3];
          *(fp16x4*)(hbuf + col * 72 + t * 16 + g * 4) = hw;
        }
      }
    }
    // ---- n-tile accumulator init = bhn (broadcast LDS read) ----
    #pragma unroll
    for (int t = 0; t < 4; ++t) acc[8 + t] = *(const f32x4*)(sbh + t * 16 + g * 4);
    // ---- B-fragments of h_old ----
    fp16x4 bb[4];
    #pragma unroll
    for (int kt = 0; kt < 4; ++kt) bb[kt] = *(const fp16x4*)(hbuf + col * 72 + kt * 16 + g * 4);
    // ---- gates: 48 MFMA ----
    #pragma unroll
    for (int mt = 0; mt < 12; ++mt) {
      #pragma unroll
      for (int kt = 0; kt < 4; ++kt) acc[mt] = MFMA16(aW[mt][kt], bb[kt], acc[mt]);
    }
    // ---- GRU elementwise (per-lane, C-layout aligned with h) ----
    #pragma unroll
    for (int t = 0; t < 4; ++t) {
      #pragma unroll
      for (int r = 0; r < 4; ++r) {
        float ar = acc[t][r];                // G_r + ir (xi preloaded as C-init)
        float az = acc[4 + t][r];            // G_z + iz
        float anb = acc[8 + t][r];           // G_n + bhn
        float rr = __builtin_amdgcn_rcpf(1.f + __expf(-ar));
        float zz = __builtin_amdgcn_rcpf(1.f + __expf(-az));
        float pre = xvn[t][r] + rr * anb;
        float nn = 1.f - 2.f * __builtin_amdgcn_rcpf(1.f + __expf(2.f * pre));
        h4[t][r] = (1.f - zz) * nn + zz * h4[t][r];
      }
    }
    // ---- write h_new (doubles as next step's h_old), read B2 ----
    if (col < 8) {
      #pragma unroll
      for (int t = 0; t < 4; ++t) {
        fp16x4 hw; hw[0]=(__fp16)h4[t][0]; hw[1]=(__fp16)h4[t][1]; hw[2]=(__fp16)h4[t][2]; hw[3]=(__fp16)h4[t][3];
        *(fp16x4*)(hbuf + col * 72 + t * 16 + g * 4) = hw;
      }
    }
    fp16x4 b2[4];
    #pragma unroll
    for (int kt = 0; kt < 4; ++kt) b2[kt] = *(const fp16x4*)(hbuf + col * 72 + kt * 16 + g * 4);
    // ---- logits: 8 MFMA ----
    f32x4 ac0 = *(const f32x4*)(sbo + g * 4);
    f32x4 ac1 = *(const f32x4*)(sbo + 16);
    #pragma unroll
    for (int kt = 0; kt < 4; ++kt) {
      ac0 = MFMA16(aO[0][kt], b2[kt], ac0);
      ac1 = MFMA16(aO[1][kt], b2[kt], ac1);
    }
    // ---- softmax (no max pass; logits small) ----
    float es = 0.f, la = 0.f;
    #pragma unroll
    for (int r = 0; r < 4; ++r) {
      float L = ac0[r];
      es += __expf(L);
      la += (g * 4 + r == act) ? L : 0.f;
    }
    if (g == 0) {
      float L16 = ac1[0], L17 = ac1[1];
      es += __expf(L16) + __expf(L17);
      la += (act == 16 ? L16 : 0.f) + (act == 17 ? L17 : 0.f);
    }
    es += __shfl_xor(es, 16); es += __shfl_xor(es, 32);
    la += __shfl_xor(la, 16); la += __shfl_xor(la, 32);
    if (lane < 8 && live) atomicAdd(&out[1 + scnt * 64 + b], __logf(es) - la);
    // ---- transition ----
    bool end = (d > 0.f) || (u == 127);
    unsigned long long bal = __ballot(end && live);
    unsigned mask8 = (unsigned)bal & 0xFFu;
    if (mask8) {
      int nb = 0;
      if (lane == 0) nb = (int)atomicAdd(ctr, (unsigned)__popc(mask8));
      nb = __shfl(nb, 0);
      if (end && live) {
        int nidx = nb + __popc(mask8 & ((1u << slot) - 1u));
        if (nidx < 8192) { u = nidx >> 6; b = nidx & 63; scnt = 0; fresh = true; }
        else live = false;
      }
    }
    if (live && !end) { u++; scnt++; }
    pair = u * 64 + b;
    // ---- prefetch next step ----
    d = dones[pair];
    act = actions[pair];
    #pragma unroll
    for (int mt = 0; mt < 8; ++mt) acc[mt] = *(const f32x4*)(xi + pair * 192 + mt * 16 + g * 4);
    #pragma unroll
    for (int t = 0; t < 4; ++t) xvn[t] = *(const f32x4*)(xi + pair * 192 + 128 + t * 16 + g * 4);
  }
}

extern "C" void kernel_launch(void* const* d_in, const int* in_sizes, int n_in,
                              void* d_out, int out_size, void* d_ws, size_t ws_size,
                              hipStream_t stream) {
  const float* state = (const float*)d_in[0];
  const float* lm    = (const float*)d_in[1];
  const float* lv    = (const float*)d_in[2];
  const float* lmt   = (const float*)d_in[3];
  const float* lvt   = (const float*)d_in[4];
  const float* ac    = (const float*)d_in[5];
  const float* ms    = (const float*)d_in[6];
  const int*   actions = (const int*)d_in[7];
  const float* dones = (const float*)d_in[8];
  const float* Wst = (const float*)d_in[9],  *bst = (const float*)d_in[10];
  const float* Wac = (const float*)d_in[11], *bac = (const float*)d_in[12];
  const float* Wem = (const float*)d_in[13], *bem = (const float*)d_in[14];
  const float* Whd = (const float*)d_in[15], *bhd = (const float*)d_in[16];
  const float* Wi  = (const float*)d_in[17], *bi  = (const float*)d_in[18];
  const float* Whrz = (const float*)d_in[19];
  const float* Whn  = (const float*)d_in[20], *bhn = (const float*)d_in[21];
  const float* Wout = (const float*)d_in[22], *bout = (const float*)d_in[23];
  float* out = (float*)d_out;
  float* xi   = (float*)((char*)d_ws + XI_OFF);
  float* hid0 = (float*)((char*)d_ws + HID_OFF);
  unsigned int* ctr = (unsigned int*)((char*)d_ws + CTR_OFF);

  hipMemsetAsync(d_out, 0, (size_t)out_size * sizeof(float), stream);
  hipMemsetAsync(ctr, 0, sizeof(unsigned int), stream);

  hipLaunchKernelGGL(precompute_kernel, dim3(320), dim3(256), 0, stream,
                     state, ac, ms, Wst, bst, Wac, bac, Wem, bem, Whd, bhd, Wi, bi,
                     lm, lv, lmt, lvt, xi, hid0, out);
  hipLaunchKernelGGL(rollout_kernel, dim3(1024), dim3(64), 0, stream,
                     xi, hid0, dones, actions, Whrz, Whn, bhn, Wout, bout, out, ctr);
}

// Round 11
// 214.594 us; speedup vs baseline: 1.5651x; 1.5651x over previous
//
#include <hip/hip_runtime.h>

// Problem: T=128, B=64, STATE=32, LATENT=16, AC=8, MS=8, SE=64, AE=16, H=64, OUT=18
// d_out layout: [0] = kl_loss, [1 .. 8192] = recon_loss[s*64+b]  (out_size = 8193, f32)
// d_ws layout:  [0, 6291456)  xi  (T,B,192) f32   = embed@Wi + bi
//               [6291456, 8388608) hid0 (T,B,64) f32
//               [8388608, +4) work-steal counter

#define XI_OFF   0
#define HID_OFF  6291456
#define CTR_OFF  8388608

typedef float f32x16 __attribute__((ext_vector_type(16)));
typedef _Float16 h2 __attribute__((ext_vector_type(2)));

#if __has_builtin(__builtin_amdgcn_fdot2)
#define DOT2(a, b, c) __builtin_amdgcn_fdot2((a), (b), (c), false)
#else
#define DOT2(a, b, c) ((c) + (float)(a).x * (float)(b).x + (float)(a).y * (float)(b).y)
#endif

// pack {h[lane], h[lane^1]} into h2 using DPP quad_perm [1,0,3,2] (VALU, no LDS)
__device__ __forceinline__ h2 pack_pair(float h) {
  int hb = __builtin_bit_cast(int, h);
  int hp = __builtin_amdgcn_mov_dpp(hb, 0xB1, 0xF, 0xF, true);  // lane^1
  return __builtin_bit_cast(h2, __builtin_amdgcn_cvt_pkrtz(h, __builtin_bit_cast(float, hp)));
}

// ---------------- Fused precompute (blocks 0..255) + KL (blocks 256..319) ----------------
__global__ __launch_bounds__(256, 1) void precompute_kernel(
    const float* __restrict__ state, const float* __restrict__ ac, const float* __restrict__ ms,
    const float* __restrict__ Wst, const float* __restrict__ bst,
    const float* __restrict__ Wac, const float* __restrict__ bac,
    const float* __restrict__ Wem, const float* __restrict__ bem,
    const float* __restrict__ Whd, const float* __restrict__ bhd,
    const float* __restrict__ Wi,  const float* __restrict__ bi,
    const float* __restrict__ lm, const float* __restrict__ lv,
    const float* __restrict__ lmt, const float* __restrict__ lvt,
    float* __restrict__ xi, float* __restrict__ hid0, float* __restrict__ out) {
  __shared__ float sWst[32 * 64];
  __shared__ float sWem[80 * 64];
  __shared__ float sWhd[24 * 64];
  __shared__ float sWac[8 * 16];
  __shared__ float sb[208];
  __shared__ float sin_[4][48];
  __shared__ float sse[4][80];
  __shared__ float semb[4][64];
  __shared__ float ps[4];
  int tid = threadIdx.x, lane = tid & 63, w = tid >> 6;

  if (blockIdx.x >= 256) {
    // ---- KL: 64 blocks * 256 threads * 16 iters = 262144 items ----
    float total = 0.f;
    for (int it = 0; it < 16; ++it) {
      int idx = ((int)blockIdx.x - 256) * 256 + tid + it * 16384;
      int g = idx & 31;
      int pair = idx >> 5;
      const float* M = (g < 16) ? lm : lmt;
      const float* V = (g < 16) ? lv : lvt;
      int cur = pair * 16 + (g & 15);
      float mu = M[cur], lE = V[cur];
      float m = 0.f, lS = 0.f;
      if (pair >= 64) { m = M[cur - 1024]; lS = V[cur - 1024]; }
      float d = m - mu;
      total += 0.5f * (lS - lE - 1.f + __expf(lE - lS) + d * d * __expf(-lS));
    }
    #pragma unroll
    for (int off = 32; off; off >>= 1) total += __shfl_xor(total, off);
    if (lane == 0) ps[w] = total;
    __syncthreads();
    if (tid == 0) atomicAdd(out, ps[0] + ps[1] + ps[2] + ps[3]);
    return;
  }

  // ---- precompute: 32 (t,b) pairs per block ----
  f32x16 wi0[4], wi1[4], wi2[4];
  #pragma unroll
  for (int k = 0; k < 64; ++k) {
    wi0[k >> 4][k & 15] = Wi[k * 192 + lane];
    wi1[k >> 4][k & 15] = Wi[k * 192 + 64 + lane];
    wi2[k >> 4][k & 15] = Wi[k * 192 + 128 + lane];
  }
  for (int i = tid; i < 32 * 64; i += 256) sWst[i] = Wst[i];
  for (int i = tid; i < 80 * 64; i += 256) sWem[i] = Wem[i];
  for (int i = tid; i < 24 * 64; i += 256) sWhd[i] = Whd[i];
  for (int i = tid; i < 8 * 16; i += 256) sWac[i] = Wac[i];
  if (tid < 64) sb[tid] = bst[tid];
  if (tid < 16) sb[64 + tid] = bac[tid];
  if (tid < 64) sb[80 + tid] = bem[tid];
  if (tid < 64) sb[144 + tid] = bhd[tid];
  float bi0 = bi[lane], bi1 = bi[64 + lane], bi2 = bi[128 + lane];
  __syncthreads();
  for (int cnt = 0; cnt < 8; ++cnt) {
    int pair = blockIdx.x * 32 + w * 8 + cnt;   // t*64 + b, in [0, 8192)
    if (lane < 32)      sin_[w][lane] = state[pair * 32 + lane];
    else if (lane < 40) sin_[w][lane] = ac[pair * 8 + (lane - 32)];
    else if (lane < 48) sin_[w][lane] = ms[pair * 8 + (lane - 40)];
    __syncthreads();
    float se = sb[lane];
    #pragma unroll
    for (int k = 0; k < 32; ++k) se += sin_[w][k] * sWst[k * 64 + lane];
    se = fmaxf(se, 0.f);
    float ae = 0.f;
    if (lane < 16) {
      ae = sb[64 + lane];
      #pragma unroll
      for (int k = 0; k < 8; ++k) ae += sin_[w][32 + k] * sWac[k * 16 + lane];
      ae = fmaxf(ae, 0.f);
    }
    __syncthreads();
    sse[w][lane] = se;
    if (lane < 16) sse[w][64 + lane] = ae;
    __syncthreads();
    float em = sb[80 + lane];
    #pragma unroll
    for (int k = 0; k < 80; ++k) em += sse[w][k] * sWem[k * 64 + lane];
    float hd = sb[144 + lane];
    #pragma unroll
    for (int k = 0; k < 16; ++k) hd += sse[w][64 + k] * sWhd[k * 64 + lane];
    #pragma unroll
    for (int k = 0; k < 8; ++k) hd += sin_[w][40 + k] * sWhd[(16 + k) * 64 + lane];
    hid0[pair * 64 + lane] = hd;
    semb[w][lane] = em;
    __syncthreads();
    float x0 = bi0, x1 = bi1, x2 = bi2;
    #pragma unroll
    for (int k = 0; k < 64; ++k) {
      float e = semb[w][k];
      x0 += e * wi0[k >> 4][k & 15];
      x1 += e * wi1[k >> 4][k & 15];
      x2 += e * wi2[k >> 4][k & 15];
    }
    float* xo = xi + pair * 192;
    xo[lane] = x0; xo[64 + lane] = x1; xo[128 + lane] = x2;
    __syncthreads();
  }
}

// ---------------- Rollout: one wave per (t,b) sequence, work-stealing ----------------
// Byte-identical to the proven 152us round-8 kernel (VGPR=128, no spill).
// Grid raised 2048 -> 4096: at VGPR=128 the HW allows 4 waves/SIMD (16/CU);
// occupancy is set by actual VGPR allocation, not the launch_bounds cap.
__global__ __launch_bounds__(64, 2) void rollout_kernel(
    const float* __restrict__ xi, const float* __restrict__ hid0,
    const float* __restrict__ dones, const int* __restrict__ actions,
    const float* __restrict__ Whrz, const float* __restrict__ Whn,
    const float* __restrict__ bhn, const float* __restrict__ Wout,
    const float* __restrict__ bout, float* __restrict__ out,
    unsigned int* __restrict__ ctr) {
  __shared__ __attribute__((aligned(16))) h2 sh2[32];        // packed h broadcast
  __shared__ __attribute__((aligned(16))) float sloge[20];   // exp(logit); [18],[19]=0
  int lane = threadIdx.x;
  int row = (lane < 18) ? lane : 0;
  h2 Wr[32], Wz[32], Wn[32], Wo[32];   // f16-packed: 128 VGPRs total
  #pragma unroll
  for (int k = 0; k < 32; ++k) {
    Wr[k] = h2{(_Float16)Whrz[(2 * k) * 128 + lane],      (_Float16)Whrz[(2 * k + 1) * 128 + lane]};
    Wz[k] = h2{(_Float16)Whrz[(2 * k) * 128 + 64 + lane], (_Float16)Whrz[(2 * k + 1) * 128 + 64 + lane]};
    Wn[k] = h2{(_Float16)Whn[(2 * k) * 64 + lane],        (_Float16)Whn[(2 * k + 1) * 64 + lane]};
    Wo[k] = h2{(_Float16)Wout[(2 * k) * 18 + row],        (_Float16)Wout[(2 * k + 1) * 18 + row]};
  }
  if (lane < 2) sloge[18 + lane] = 0.f;          // sentinels: exp contribution 0
  float bhn_r = bhn[lane];
  float bo_r = bout[row];
  __syncthreads();
  const uint4* shv = (const uint4*)sh2;
  while (true) {
    int i = 0;
    if (lane == 0) i = (int)atomicAdd(ctr, 1u);
    i = __shfl(i, 0);
    if (i >= 8192) break;
    int t = i >> 6, b = i & 63;                  // t-ascending = longest-first (LPT)
    int u = t;
    int pr = (t << 6) | b;
    float h = hid0[pr * 64 + lane];              // covers the s=0 reset case too
    const float* xb = xi + pr * 192;
    float x0 = xb[lane], x1 = xb[64 + lane], x2 = xb[128 + lane];
    float d = dones[pr];
    int  act = actions[pr];
    if ((lane & 1) == 0) sh2[lane >> 1] = pack_pair(h);
    for (int s = 0;; ++s) {
      int un = (u < 127) ? u + 1 : 127;
      int prn = (un << 6) | b;
      // -------- prefetch next step (hidden under compute) --------
      const float* xn = xi + prn * 192;
      float nx0 = xn[lane], nx1 = xn[64 + lane], nx2 = xn[128 + lane];
      float nd = dones[prn];
      int   na = actions[prn];
      float nh = hid0[prn * 64 + lane];
      // -------- GRU gates: 8 uniform b128 reads + 96 dot2 --------
      float ara = x0, arb = 0.f, aza = x1, azb = 0.f, ana = 0.f, anb = 0.f;
      #pragma unroll
      for (int q = 0; q < 8; ++q) {
        uint4 hv = shv[q];                        // broadcast (same addr all lanes)
        h2 a0 = __builtin_bit_cast(h2, hv.x);
        h2 a1 = __builtin_bit_cast(h2, hv.y);
        h2 a2 = __builtin_bit_cast(h2, hv.z);
        h2 a3 = __builtin_bit_cast(h2, hv.w);
        ara = DOT2(a0, Wr[4 * q + 0], ara); arb = DOT2(a1, Wr[4 * q + 1], arb);
        ara = DOT2(a2, Wr[4 * q + 2], ara); arb = DOT2(a3, Wr[4 * q + 3], arb);
        aza = DOT2(a0, Wz[4 * q + 0], aza); azb = DOT2(a1, Wz[4 * q + 1], azb);
        aza = DOT2(a2, Wz[4 * q + 2], aza); azb = DOT2(a3, Wz[4 * q + 3], azb);
        ana = DOT2(a0, Wn[4 * q + 0], ana); anb = DOT2(a1, Wn[4 * q + 1], anb);
        ana = DOT2(a2, Wn[4 * q + 2], ana); anb = DOT2(a3, Wn[4 * q + 3], anb);
      }
      float ar = ara + arb, az = aza + azb, an = ana + anb;
      float r = __builtin_amdgcn_rcpf(1.f + __expf(-ar));
      float z = __builtin_amdgcn_rcpf(1.f + __expf(-az));
      float pre = x2 + r * (an + bhn_r);
      float n = 1.f - 2.f * __builtin_amdgcn_rcpf(1.f + __expf(2.f * pre));  // tanh
      float hn = (1.f - z) * n + z * h;
      // -------- broadcast h_new; logits via register W_out rows --------
      if ((lane & 1) == 0) sh2[lane >> 1] = pack_pair(hn);
      float la_a = bo_r, la_b = 0.f;
      #pragma unroll
      for (int q = 0; q < 8; ++q) {
        uint4 hv = shv[q];
        la_a = DOT2(__builtin_bit_cast(h2, hv.x), Wo[4 * q + 0], la_a);
        la_b = DOT2(__builtin_bit_cast(h2, hv.y), Wo[4 * q + 1], la_b);
        la_a = DOT2(__builtin_bit_cast(h2, hv.z), Wo[4 * q + 2], la_a);
        la_b = DOT2(__builtin_bit_cast(h2, hv.w), Wo[4 * q + 3], la_b);
      }
      float logit = la_a + la_b;
      // -------- softmax without max pass (|logit| small by construction) --------
      if (lane < 18) sloge[lane] = __expf(logit);
      float4 e0 = *(const float4*)&sloge[0];
      float4 e1 = *(const float4*)&sloge[4];
      float4 e2 = *(const float4*)&sloge[8];
      float4 e3 = *(const float4*)&sloge[12];
      float4 e4 = *(const float4*)&sloge[16];    // [18],[19] are 0
      float ssum = (((e0.x + e0.y) + (e0.z + e0.w)) + ((e1.x + e1.y) + (e1.z + e1.w)))
                 + (((e2.x + e2.y) + (e2.z + e2.w)) + ((e3.x + e3.y) + (e3.z + e3.w)))
                 + ((e4.x + e4.y) + (e4.z + e4.w));
      float la = __builtin_bit_cast(float, __builtin_amdgcn_readlane(__builtin_bit_cast(int, logit), act));
      float lse = __logf(ssum);
      if (lane == 0) atomicAdd(&out[1 + s * 64 + b], lse - la);
      if (d > 0.f || u == 127) break;            // mask is 0 for all later steps
      // -------- advance --------
      u = un; x0 = nx0; x1 = nx1; x2 = nx2; d = nd; act = na;
      if (nd > 0.f) {
        h = nh;                                  // episode reset at next step start
        if ((lane & 1) == 0) sh2[lane >> 1] = pack_pair(h);
      } else {
        h = hn;                                  // sh2 already holds hn
      }
    }
  }
}

extern "C" void kernel_launch(void* const* d_in, const int* in_sizes, int n_in,
                              void* d_out, int out_size, void* d_ws, size_t ws_size,
                              hipStream_t stream) {
  const float* state = (const float*)d_in[0];
  const float* lm    = (const float*)d_in[1];
  const float* lv    = (const float*)d_in[2];
  const float* lmt   = (const float*)d_in[3];
  const float* lvt   = (const float*)d_in[4];
  const float* ac    = (const float*)d_in[5];
  const float* ms    = (const float*)d_in[6];
  const int*   actions = (const int*)d_in[7];
  const float* dones = (const float*)d_in[8];
  const float* Wst = (const float*)d_in[9],  *bst = (const float*)d_in[10];
  const float* Wac = (const float*)d_in[11], *bac = (const float*)d_in[12];
  const float* Wem = (const float*)d_in[13], *bem = (const float*)d_in[14];
  const float* Whd = (const float*)d_in[15], *bhd = (const float*)d_in[16];
  const float* Wi  = (const float*)d_in[17], *bi  = (const float*)d_in[18];
  const float* Whrz = (const float*)d_in[19];
  const float* Whn  = (const float*)d_in[20], *bhn = (const float*)d_in[21];
  const float* Wout = (const float*)d_in[22], *bout = (const float*)d_in[23];
  float* out = (float*)d_out;
  float* xi   = (float*)((char*)d_ws + XI_OFF);
  float* hid0 = (float*)((char*)d_ws + HID_OFF);
  unsigned int* ctr = (unsigned int*)((char*)d_ws + CTR_OFF);

  hipMemsetAsync(d_out, 0, (size_t)out_size * sizeof(float), stream);
  hipMemsetAsync(ctr, 0, sizeof(unsigned int), stream);

  hipLaunchKernelGGL(precompute_kernel, dim3(320), dim3(256), 0, stream,
                     state, ac, ms, Wst, bst, Wac, bac, Wem, bem, Whd, bhd, Wi, bi,
                     lm, lv, lmt, lvt, xi, hid0, out);
  hipLaunchKernelGGL(rollout_kernel, dim3(4096), dim3(64), 0, stream,
                     xi, hid0, dones, actions, Whrz, Whn, bhn, Wout, bout, out, ctr);
}

// Round 12
// 197.888 us; speedup vs baseline: 1.6972x; 1.0844x over previous
//
#include <hip/hip_runtime.h>

// Problem: T=128, B=64, STATE=32, LATENT=16, AC=8, MS=8, SE=64, AE=16, H=64, OUT=18
// d_out layout: [0] = kl_loss, [1 .. 8192] = recon_loss[s*64+b]  (out_size = 8193, f32)
// d_ws layout:  [0, 6291456)  xi  (T,B,192) f32   = embed@Wi + bi
//               [6291456, 8388608) hid0 (T,B,64) f32
//               [8388608, +4) work-steal counter

#define XI_OFF   0
#define HID_OFF  6291456
#define CTR_OFF  8388608

typedef float f32x16 __attribute__((ext_vector_type(16)));
typedef _Float16 h2 __attribute__((ext_vector_type(2)));

#if __has_builtin(__builtin_amdgcn_fdot2)
#define DOT2(a, b, c) __builtin_amdgcn_fdot2((a), (b), (c), false)
#else
#define DOT2(a, b, c) ((c) + (float)(a).x * (float)(b).x + (float)(a).y * (float)(b).y)
#endif

// pack {h[lane], h[lane^1]} into h2 using DPP quad_perm [1,0,3,2] (VALU, no LDS)
__device__ __forceinline__ h2 pack_pair(float h) {
  int hb = __builtin_bit_cast(int, h);
  int hp = __builtin_amdgcn_mov_dpp(hb, 0xB1, 0xF, 0xF, true);  // lane^1
  return __builtin_bit_cast(h2, __builtin_amdgcn_cvt_pkrtz(h, __builtin_bit_cast(float, hp)));
}

// ---------------- Fused precompute (blocks 0..255) + KL (blocks 256..319) ----------------
__global__ __launch_bounds__(256, 1) void precompute_kernel(
    const float* __restrict__ state, const float* __restrict__ ac, const float* __restrict__ ms,
    const float* __restrict__ Wst, const float* __restrict__ bst,
    const float* __restrict__ Wac, const float* __restrict__ bac,
    const float* __restrict__ Wem, const float* __restrict__ bem,
    const float* __restrict__ Whd, const float* __restrict__ bhd,
    const float* __restrict__ Wi,  const float* __restrict__ bi,
    const float* __restrict__ lm, const float* __restrict__ lv,
    const float* __restrict__ lmt, const float* __restrict__ lvt,
    float* __restrict__ xi, float* __restrict__ hid0, float* __restrict__ out) {
  __shared__ float sWst[32 * 64];
  __shared__ float sWem[80 * 64];
  __shared__ float sWhd[24 * 64];
  __shared__ float sWac[8 * 16];
  __shared__ float sb[208];
  __shared__ float sin_[4][48];
  __shared__ float sse[4][80];
  __shared__ float semb[4][64];
  __shared__ float ps[4];
  int tid = threadIdx.x, lane = tid & 63, w = tid >> 6;

  if (blockIdx.x >= 256) {
    // ---- KL: 64 blocks * 256 threads * 16 iters = 262144 items ----
    float total = 0.f;
    for (int it = 0; it < 16; ++it) {
      int idx = ((int)blockIdx.x - 256) * 256 + tid + it * 16384;
      int g = idx & 31;
      int pair = idx >> 5;
      const float* M = (g < 16) ? lm : lmt;
      const float* V = (g < 16) ? lv : lvt;
      int cur = pair * 16 + (g & 15);
      float mu = M[cur], lE = V[cur];
      float m = 0.f, lS = 0.f;
      if (pair >= 64) { m = M[cur - 1024]; lS = V[cur - 1024]; }
      float d = m - mu;
      total += 0.5f * (lS - lE - 1.f + __expf(lE - lS) + d * d * __expf(-lS));
    }
    #pragma unroll
    for (int off = 32; off; off >>= 1) total += __shfl_xor(total, off);
    if (lane == 0) ps[w] = total;
    __syncthreads();
    if (tid == 0) atomicAdd(out, ps[0] + ps[1] + ps[2] + ps[3]);
    return;
  }

  // ---- precompute: 32 (t,b) pairs per block ----
  f32x16 wi0[4], wi1[4], wi2[4];
  #pragma unroll
  for (int k = 0; k < 64; ++k) {
    wi0[k >> 4][k & 15] = Wi[k * 192 + lane];
    wi1[k >> 4][k & 15] = Wi[k * 192 + 64 + lane];
    wi2[k >> 4][k & 15] = Wi[k * 192 + 128 + lane];
  }
  for (int i = tid; i < 32 * 64; i += 256) sWst[i] = Wst[i];
  for (int i = tid; i < 80 * 64; i += 256) sWem[i] = Wem[i];
  for (int i = tid; i < 24 * 64; i += 256) sWhd[i] = Whd[i];
  for (int i = tid; i < 8 * 16; i += 256) sWac[i] = Wac[i];
  if (tid < 64) sb[tid] = bst[tid];
  if (tid < 16) sb[64 + tid] = bac[tid];
  if (tid < 64) sb[80 + tid] = bem[tid];
  if (tid < 64) sb[144 + tid] = bhd[tid];
  float bi0 = bi[lane], bi1 = bi[64 + lane], bi2 = bi[128 + lane];
  __syncthreads();
  for (int cnt = 0; cnt < 8; ++cnt) {
    int pair = blockIdx.x * 32 + w * 8 + cnt;   // t*64 + b, in [0, 8192)
    if (lane < 32)      sin_[w][lane] = state[pair * 32 + lane];
    else if (lane < 40) sin_[w][lane] = ac[pair * 8 + (lane - 32)];
    else if (lane < 48) sin_[w][lane] = ms[pair * 8 + (lane - 40)];
    __syncthreads();
    float se = sb[lane];
    #pragma unroll
    for (int k = 0; k < 32; ++k) se += sin_[w][k] * sWst[k * 64 + lane];
    se = fmaxf(se, 0.f);
    float ae = 0.f;
    if (lane < 16) {
      ae = sb[64 + lane];
      #pragma unroll
      for (int k = 0; k < 8; ++k) ae += sin_[w][32 + k] * sWac[k * 16 + lane];
      ae = fmaxf(ae, 0.f);
    }
    __syncthreads();
    sse[w][lane] = se;
    if (lane < 16) sse[w][64 + lane] = ae;
    __syncthreads();
    float em = sb[80 + lane];
    #pragma unroll
    for (int k = 0; k < 80; ++k) em += sse[w][k] * sWem[k * 64 + lane];
    float hd = sb[144 + lane];
    #pragma unroll
    for (int k = 0; k < 16; ++k) hd += sse[w][64 + k] * sWhd[k * 64 + lane];
    #pragma unroll
    for (int k = 0; k < 8; ++k) hd += sin_[w][40 + k] * sWhd[(16 + k) * 64 + lane];
    hid0[pair * 64 + lane] = hd;
    semb[w][lane] = em;
    __syncthreads();
    float x0 = bi0, x1 = bi1, x2 = bi2;
    #pragma unroll
    for (int k = 0; k < 64; ++k) {
      float e = semb[w][k];
      x0 += e * wi0[k >> 4][k & 15];
      x1 += e * wi1[k >> 4][k & 15];
      x2 += e * wi2[k >> 4][k & 15];
    }
    float* xo = xi + pair * 192;
    xo[lane] = x0; xo[64 + lane] = x1; xo[128 + lane] = x2;
    __syncthreads();
  }
}

// ---------------- Rollout: one wave per (t,b) sequence, DEFERRED LOGITS ----------------
// logits(s-1) computed at step s from the SAME 8 uniform b128 h-fragment reads as
// gates(s) (h_old(s) == h_new(s-1) when no reset). Softmax/emit moves off the
// recurrence critical path. Flush pass on sequence end / episode reset (~11% of steps).
// DS ops/step: 25 -> 15. Occupancy capped at 2 waves/SIMD by ~256 total regs.
__global__ __launch_bounds__(64, 2) void rollout_kernel(
    const float* __restrict__ xi, const float* __restrict__ hid0,
    const float* __restrict__ dones, const int* __restrict__ actions,
    const float* __restrict__ Whrz, const float* __restrict__ Whn,
    const float* __restrict__ bhn, const float* __restrict__ Wout,
    const float* __restrict__ bout, float* __restrict__ out,
    unsigned int* __restrict__ ctr) {
  __shared__ __attribute__((aligned(16))) h2 sh2[32];        // packed h broadcast
  __shared__ __attribute__((aligned(16))) float sloge[20];   // exp(logit); [18],[19]=0
  int lane = threadIdx.x;
  int row = (lane < 18) ? lane : 0;
  h2 Wr[32], Wz[32], Wn[32], Wo[32];   // f16-packed: 128 regs total (V+A unified)
  #pragma unroll
  for (int k = 0; k < 32; ++k) {
    Wr[k] = h2{(_Float16)Whrz[(2 * k) * 128 + lane],      (_Float16)Whrz[(2 * k + 1) * 128 + lane]};
    Wz[k] = h2{(_Float16)Whrz[(2 * k) * 128 + 64 + lane], (_Float16)Whrz[(2 * k + 1) * 128 + 64 + lane]};
    Wn[k] = h2{(_Float16)Whn[(2 * k) * 64 + lane],        (_Float16)Whn[(2 * k + 1) * 64 + lane]};
    Wo[k] = h2{(_Float16)Wout[(2 * k) * 18 + row],        (_Float16)Wout[(2 * k + 1) * 18 + row]};
  }
  if (lane < 2) sloge[18 + lane] = 0.f;          // sentinels: exp contribution 0
  float bhn_r = bhn[lane];
  float bo_r = bout[row];
  __syncthreads();
  const uint4* shv = (const uint4*)sh2;
  while (true) {
    int i = 0;
    if (lane == 0) i = (int)atomicAdd(ctr, 1u);
    i = __shfl(i, 0);
    if (i >= 8192) break;
    int t = i >> 6, b = i & 63;                  // t-ascending = longest-first (LPT)
    int u = t;
    int pr = (t << 6) | b;
    float h = hid0[pr * 64 + lane];              // covers the s=0 reset case too
    const float* xb = xi + pr * 192;
    float x0 = xb[lane], x1 = xb[64 + lane], x2 = xb[128 + lane];
    float d = dones[pr];
    int  act = actions[pr];
    if ((lane & 1) == 0) sh2[lane >> 1] = pack_pair(h);
    bool pend = false; int pssave = 0, pact = 0;
    for (int s = 0;; ++s) {
      int un = (u < 127) ? u + 1 : 127;
      int prn = (un << 6) | b;
      // -------- prefetch next step (hidden under compute) --------
      const float* xn = xi + prn * 192;
      float nx0 = xn[lane], nx1 = xn[64 + lane], nx2 = xn[128 + lane];
      float nd = dones[prn];
      int   na = actions[prn];
      float nh = hid0[prn * 64 + lane];
      // -------- SINGLE fragment pass: gates(s) + deferred logits(s-1) --------
      float ara = x0, arb = 0.f, aza = x1, azb = 0.f, ana = 0.f, anb = 0.f;
      float pla = bo_r, plb = 0.f;
      #pragma unroll
      for (int q = 0; q < 8; ++q) {
        uint4 hv = shv[q];                        // broadcast (same addr all lanes)
        h2 a0 = __builtin_bit_cast(h2, hv.x);
        h2 a1 = __builtin_bit_cast(h2, hv.y);
        h2 a2 = __builtin_bit_cast(h2, hv.z);
        h2 a3 = __builtin_bit_cast(h2, hv.w);
        ara = DOT2(a0, Wr[4 * q + 0], ara); arb = DOT2(a1, Wr[4 * q + 1], arb);
        ara = DOT2(a2, Wr[4 * q + 2], ara); arb = DOT2(a3, Wr[4 * q + 3], arb);
        aza = DOT2(a0, Wz[4 * q + 0], aza); azb = DOT2(a1, Wz[4 * q + 1], azb);
        aza = DOT2(a2, Wz[4 * q + 2], aza); azb = DOT2(a3, Wz[4 * q + 3], azb);
        ana = DOT2(a0, Wn[4 * q + 0], ana); anb = DOT2(a1, Wn[4 * q + 1], anb);
        ana = DOT2(a2, Wn[4 * q + 2], ana); anb = DOT2(a3, Wn[4 * q + 3], anb);
        pla = DOT2(a0, Wo[4 * q + 0], pla); plb = DOT2(a1, Wo[4 * q + 1], plb);
        pla = DOT2(a2, Wo[4 * q + 2], pla); plb = DOT2(a3, Wo[4 * q + 3], plb);
      }
      // -------- emit pending logits(s-1) — off the recurrence critical path ------
      float plog = pla + plb;
      if (lane < 18) sloge[lane] = __expf(plog);
      // -------- GRU nonlinearity (the critical chain) --------
      float ar = ara + arb, az = aza + azb, an = ana + anb;
      float r = __builtin_amdgcn_rcpf(1.f + __expf(-ar));
      float z = __builtin_amdgcn_rcpf(1.f + __expf(-az));
      float pre = x2 + r * (an + bhn_r);
      float n = 1.f - 2.f * __builtin_amdgcn_rcpf(1.f + __expf(2.f * pre));  // tanh
      float hn = (1.f - z) * n + z * h;
      if ((lane & 1) == 0) sh2[lane >> 1] = pack_pair(hn);  // h for next step
      // -------- finish pending softmax --------
      float4 e0 = *(const float4*)&sloge[0];
      float4 e1 = *(const float4*)&sloge[4];
      float4 e2 = *(const float4*)&sloge[8];
      float4 e3 = *(const float4*)&sloge[12];
      float4 e4 = *(const float4*)&sloge[16];    // [18],[19] are 0
      float ssum = (((e0.x + e0.y) + (e0.z + e0.w)) + ((e1.x + e1.y) + (e1.z + e1.w)))
                 + (((e2.x + e2.y) + (e2.z + e2.w)) + ((e3.x + e3.y) + (e3.z + e3.w)))
                 + ((e4.x + e4.y) + (e4.z + e4.w));
      if (pend && lane == 0) {
        float la = __builtin_bit_cast(float, __builtin_amdgcn_readlane(__builtin_bit_cast(int, plog), pact));
        atomicAdd(&out[1 + pssave * 64 + b], __logf(ssum) - la);
      }
      pend = true; pssave = s; pact = act;
      bool end = (d > 0.f) || (u == 127);
      bool rst = (!end) && (nd > 0.f);
      if (end || rst) {
        // -------- flush logits(s) from sh2 (holds hn); uniform branch, ~11% ------
        float fa = bo_r, fb = 0.f;
        #pragma unroll
        for (int q = 0; q < 8; ++q) {
          uint4 hv = shv[q];
          fa = DOT2(__builtin_bit_cast(h2, hv.x), Wo[4 * q + 0], fa);
          fb = DOT2(__builtin_bit_cast(h2, hv.y), Wo[4 * q + 1], fb);
          fa = DOT2(__builtin_bit_cast(h2, hv.z), Wo[4 * q + 2], fa);
          fb = DOT2(__builtin_bit_cast(h2, hv.w), Wo[4 * q + 3], fb);
        }
        float flog = fa + fb;
        if (lane < 18) sloge[lane] = __expf(flog);
        float4 f0 = *(const float4*)&sloge[0];
        float4 f1 = *(const float4*)&sloge[4];
        float4 f2 = *(const float4*)&sloge[8];
        float4 f3 = *(const float4*)&sloge[12];
        float4 f4 = *(const float4*)&sloge[16];
        float fsum = (((f0.x + f0.y) + (f0.z + f0.w)) + ((f1.x + f1.y) + (f1.z + f1.w)))
                   + (((f2.x + f2.y) + (f2.z + f2.w)) + ((f3.x + f3.y) + (f3.z + f3.w)))
                   + ((f4.x + f4.y) + (f4.z + f4.w));
        if (lane == 0) {
          float fla = __builtin_bit_cast(float, __builtin_amdgcn_readlane(__builtin_bit_cast(int, flog), act));
          atomicAdd(&out[1 + s * 64 + b], __logf(fsum) - fla);
        }
        pend = false;
        if (end) break;
        // episode reset: restart h from hid0[u+1]
        h = nh;
        if ((lane & 1) == 0) sh2[lane >> 1] = pack_pair(nh);
        u = un; x0 = nx0; x1 = nx1; x2 = nx2; d = nd; act = na;
        continue;
      }
      // -------- normal advance --------
      h = hn;
      u = un; x0 = nx0; x1 = nx1; x2 = nx2; d = nd; act = na;
    }
  }
}

extern "C" void kernel_launch(void* const* d_in, const int* in_sizes, int n_in,
                              void* d_out, int out_size, void* d_ws, size_t ws_size,
                              hipStream_t stream) {
  const float* state = (const float*)d_in[0];
  const float* lm    = (const float*)d_in[1];
  const float* lv    = (const float*)d_in[2];
  const float* lmt   = (const float*)d_in[3];
  const float* lvt   = (const float*)d_in[4];
  const float* ac    = (const float*)d_in[5];
  const float* ms    = (const float*)d_in[6];
  const int*   actions = (const int*)d_in[7];
  const float* dones = (const float*)d_in[8];
  const float* Wst = (const float*)d_in[9],  *bst = (const float*)d_in[10];
  const float* Wac = (const float*)d_in[11], *bac = (const float*)d_in[12];
  const float* Wem = (const float*)d_in[13], *bem = (const float*)d_in[14];
  const float* Whd = (const float*)d_in[15], *bhd = (const float*)d_in[16];
  const float* Wi  = (const float*)d_in[17], *bi  = (const float*)d_in[18];
  const float* Whrz = (const float*)d_in[19];
  const float* Whn  = (const float*)d_in[20], *bhn = (const float*)d_in[21];
  const float* Wout = (const float*)d_in[22], *bout = (const float*)d_in[23];
  float* out = (float*)d_out;
  float* xi   = (float*)((char*)d_ws + XI_OFF);
  float* hid0 = (float*)((char*)d_ws + HID_OFF);
  unsigned int* ctr = (unsigned int*)((char*)d_ws + CTR_OFF);

  hipMemsetAsync(d_out, 0, (size_t)out_size * sizeof(float), stream);
  hipMemsetAsync(ctr, 0, sizeof(unsigned int), stream);

  hipLaunchKernelGGL(precompute_kernel, dim3(320), dim3(256), 0, stream,
                     state, ac, ms, Wst, bst, Wac, bac, Wem, bem, Whd, bhd, Wi, bi,
                     lm, lv, lmt, lvt, xi, hid0, out);
  hipLaunchKernelGGL(rollout_kernel, dim3(2048), dim3(64), 0, stream,
                     xi, hid0, dones, actions, Whrz, Whn, bhn, Wout, bout, out, ctr);
}

// Round 13
// 195.167 us; speedup vs baseline: 1.7209x; 1.0139x over previous
//
#include <hip/hip_runtime.h>

// Problem: T=128, B=64, STATE=32, LATENT=16, AC=8, MS=8, SE=64, AE=16, H=64, OUT=18
// d_out layout: [0] = kl_loss, [1 .. 8192] = recon_loss[s*64+b]  (out_size = 8193, f32)
// d_ws layout:  [0, 6291456)  xi  (T,B,192) f32   = embed@Wi + bi
//               [6291456, 8388608) hid0 (T,B,64) f32
//               [8388608, +4) work-steal counter

#define XI_OFF   0
#define HID_OFF  6291456
#define CTR_OFF  8388608

typedef float f32x16 __attribute__((ext_vector_type(16)));
typedef _Float16 h2 __attribute__((ext_vector_type(2)));

#if __has_builtin(__builtin_amdgcn_fdot2)
#define DOT2(a, b, c) __builtin_amdgcn_fdot2((a), (b), (c), false)
#else
#define DOT2(a, b, c) ((c) + (float)(a).x * (float)(b).x + (float)(a).y * (float)(b).y)
#endif

// pack {h[lane], h[lane^1]} into h2 using DPP quad_perm [1,0,3,2] (VALU, no LDS)
__device__ __forceinline__ h2 pack_pair(float h) {
  int hb = __builtin_bit_cast(int, h);
  int hp = __builtin_amdgcn_mov_dpp(hb, 0xB1, 0xF, 0xF, true);  // lane^1
  return __builtin_bit_cast(h2, __builtin_amdgcn_cvt_pkrtz(h, __builtin_bit_cast(float, hp)));
}

// ---------------- Fused precompute (blocks 0..255) + KL (blocks 256..319) ----------------
__global__ __launch_bounds__(256, 1) void precompute_kernel(
    const float* __restrict__ state, const float* __restrict__ ac, const float* __restrict__ ms,
    const float* __restrict__ Wst, const float* __restrict__ bst,
    const float* __restrict__ Wac, const float* __restrict__ bac,
    const float* __restrict__ Wem, const float* __restrict__ bem,
    const float* __restrict__ Whd, const float* __restrict__ bhd,
    const float* __restrict__ Wi,  const float* __restrict__ bi,
    const float* __restrict__ lm, const float* __restrict__ lv,
    const float* __restrict__ lmt, const float* __restrict__ lvt,
    float* __restrict__ xi, float* __restrict__ hid0, float* __restrict__ out) {
  __shared__ float sWst[32 * 64];
  __shared__ float sWem[80 * 64];
  __shared__ float sWhd[24 * 64];
  __shared__ float sWac[8 * 16];
  __shared__ float sb[208];
  __shared__ float sin_[4][48];
  __shared__ float sse[4][80];
  __shared__ float semb[4][64];
  __shared__ float ps[4];
  int tid = threadIdx.x, lane = tid & 63, w = tid >> 6;

  if (blockIdx.x >= 256) {
    // ---- KL: 64 blocks * 256 threads * 16 iters = 262144 items ----
    float total = 0.f;
    for (int it = 0; it < 16; ++it) {
      int idx = ((int)blockIdx.x - 256) * 256 + tid + it * 16384;
      int g = idx & 31;
      int pair = idx >> 5;
      const float* M = (g < 16) ? lm : lmt;
      const float* V = (g < 16) ? lv : lvt;
      int cur = pair * 16 + (g & 15);
      float mu = M[cur], lE = V[cur];
      float m = 0.f, lS = 0.f;
      if (pair >= 64) { m = M[cur - 1024]; lS = V[cur - 1024]; }
      float d = m - mu;
      total += 0.5f * (lS - lE - 1.f + __expf(lE - lS) + d * d * __expf(-lS));
    }
    #pragma unroll
    for (int off = 32; off; off >>= 1) total += __shfl_xor(total, off);
    if (lane == 0) ps[w] = total;
    __syncthreads();
    if (tid == 0) atomicAdd(out, ps[0] + ps[1] + ps[2] + ps[3]);
    return;
  }

  // ---- precompute: 32 (t,b) pairs per block ----
  f32x16 wi0[4], wi1[4], wi2[4];
  #pragma unroll
  for (int k = 0; k < 64; ++k) {
    wi0[k >> 4][k & 15] = Wi[k * 192 + lane];
    wi1[k >> 4][k & 15] = Wi[k * 192 + 64 + lane];
    wi2[k >> 4][k & 15] = Wi[k * 192 + 128 + lane];
  }
  for (int i = tid; i < 32 * 64; i += 256) sWst[i] = Wst[i];
  for (int i = tid; i < 80 * 64; i += 256) sWem[i] = Wem[i];
  for (int i = tid; i < 24 * 64; i += 256) sWhd[i] = Whd[i];
  for (int i = tid; i < 8 * 16; i += 256) sWac[i] = Wac[i];
  if (tid < 64) sb[tid] = bst[tid];
  if (tid < 16) sb[64 + tid] = bac[tid];
  if (tid < 64) sb[80 + tid] = bem[tid];
  if (tid < 64) sb[144 + tid] = bhd[tid];
  float bi0 = bi[lane], bi1 = bi[64 + lane], bi2 = bi[128 + lane];
  __syncthreads();
  for (int cnt = 0; cnt < 8; ++cnt) {
    int pair = blockIdx.x * 32 + w * 8 + cnt;   // t*64 + b, in [0, 8192)
    if (lane < 32)      sin_[w][lane] = state[pair * 32 + lane];
    else if (lane < 40) sin_[w][lane] = ac[pair * 8 + (lane - 32)];
    else if (lane < 48) sin_[w][lane] = ms[pair * 8 + (lane - 40)];
    __syncthreads();
    float se = sb[lane];
    #pragma unroll
    for (int k = 0; k < 32; ++k) se += sin_[w][k] * sWst[k * 64 + lane];
    se = fmaxf(se, 0.f);
    float ae = 0.f;
    if (lane < 16) {
      ae = sb[64 + lane];
      #pragma unroll
      for (int k = 0; k < 8; ++k) ae += sin_[w][32 + k] * sWac[k * 16 + lane];
      ae = fmaxf(ae, 0.f);
    }
    __syncthreads();
    sse[w][lane] = se;
    if (lane < 16) sse[w][64 + lane] = ae;
    __syncthreads();
    float em = sb[80 + lane];
    #pragma unroll
    for (int k = 0; k < 80; ++k) em += sse[w][k] * sWem[k * 64 + lane];
    float hd = sb[144 + lane];
    #pragma unroll
    for (int k = 0; k < 16; ++k) hd += sse[w][64 + k] * sWhd[k * 64 + lane];
    #pragma unroll
    for (int k = 0; k < 8; ++k) hd += sin_[w][40 + k] * sWhd[(16 + k) * 64 + lane];
    hid0[pair * 64 + lane] = hd;
    semb[w][lane] = em;
    __syncthreads();
    float x0 = bi0, x1 = bi1, x2 = bi2;
    #pragma unroll
    for (int k = 0; k < 64; ++k) {
      float e = semb[w][k];
      x0 += e * wi0[k >> 4][k & 15];
      x1 += e * wi1[k >> 4][k & 15];
      x2 += e * wi2[k >> 4][k & 15];
    }
    float* xo = xi + pair * 192;
    xo[lane] = x0; xo[64 + lane] = x1; xo[128 + lane] = x2;
    __syncthreads();
  }
}

// ---------------- Rollout: one wave per (t,b) sequence, work-stealing ----------------
// Round-8 body with __launch_bounds__(64,1): 512-VGPR cap so ALL ~180 live values
// (incl. the 128 f16 weight regs) sit in arch VGPRs — no v_accvgpr_read per weight
// use. Occupancy stays 2 waves/SIMD either way (proven by round 11), so the cap
// costs nothing and removes the AGPR-move tax.
__global__ __launch_bounds__(64, 1) void rollout_kernel(
    const float* __restrict__ xi, const float* __restrict__ hid0,
    const float* __restrict__ dones, const int* __restrict__ actions,
    const float* __restrict__ Whrz, const float* __restrict__ Whn,
    const float* __restrict__ bhn, const float* __restrict__ Wout,
    const float* __restrict__ bout, float* __restrict__ out,
    unsigned int* __restrict__ ctr) {
  __shared__ __attribute__((aligned(16))) h2 sh2[32];        // packed h broadcast
  __shared__ __attribute__((aligned(16))) float sloge[20];   // exp(logit); [18],[19]=0
  int lane = threadIdx.x;
  int row = (lane < 18) ? lane : 0;
  h2 Wr[32], Wz[32], Wn[32], Wo[32];   // f16-packed: 128 regs
  #pragma unroll
  for (int k = 0; k < 32; ++k) {
    Wr[k] = h2{(_Float16)Whrz[(2 * k) * 128 + lane],      (_Float16)Whrz[(2 * k + 1) * 128 + lane]};
    Wz[k] = h2{(_Float16)Whrz[(2 * k) * 128 + 64 + lane], (_Float16)Whrz[(2 * k + 1) * 128 + 64 + lane]};
    Wn[k] = h2{(_Float16)Whn[(2 * k) * 64 + lane],        (_Float16)Whn[(2 * k + 1) * 64 + lane]};
    Wo[k] = h2{(_Float16)Wout[(2 * k) * 18 + row],        (_Float16)Wout[(2 * k + 1) * 18 + row]};
  }
  if (lane < 2) sloge[18 + lane] = 0.f;          // sentinels: exp contribution 0
  float bhn_r = bhn[lane];
  float bo_r = bout[row];
  __syncthreads();
  const uint4* shv = (const uint4*)sh2;
  while (true) {
    int i = 0;
    if (lane == 0) i = (int)atomicAdd(ctr, 1u);
    i = __shfl(i, 0);
    if (i >= 8192) break;
    int t = i >> 6, b = i & 63;                  // t-ascending = longest-first (LPT)
    int u = t;
    int pr = (t << 6) | b;
    float h = hid0[pr * 64 + lane];              // covers the s=0 reset case too
    const float* xb = xi + pr * 192;
    float x0 = xb[lane], x1 = xb[64 + lane], x2 = xb[128 + lane];
    float d = dones[pr];
    int  act = actions[pr];
    if ((lane & 1) == 0) sh2[lane >> 1] = pack_pair(h);
    for (int s = 0;; ++s) {
      int un = (u < 127) ? u + 1 : 127;
      int prn = (un << 6) | b;
      // -------- prefetch next step (hidden under compute) --------
      const float* xn = xi + prn * 192;
      float nx0 = xn[lane], nx1 = xn[64 + lane], nx2 = xn[128 + lane];
      float nd = dones[prn];
      int   na = actions[prn];
      float nh = hid0[prn * 64 + lane];
      // -------- GRU gates: 8 uniform b128 reads + 96 dot2 --------
      float ara = x0, arb = 0.f, aza = x1, azb = 0.f, ana = 0.f, anb = 0.f;
      #pragma unroll
      for (int q = 0; q < 8; ++q) {
        uint4 hv = shv[q];                        // broadcast (same addr all lanes)
        h2 a0 = __builtin_bit_cast(h2, hv.x);
        h2 a1 = __builtin_bit_cast(h2, hv.y);
        h2 a2 = __builtin_bit_cast(h2, hv.z);
        h2 a3 = __builtin_bit_cast(h2, hv.w);
        ara = DOT2(a0, Wr[4 * q + 0], ara); arb = DOT2(a1, Wr[4 * q + 1], arb);
        ara = DOT2(a2, Wr[4 * q + 2], ara); arb = DOT2(a3, Wr[4 * q + 3], arb);
        aza = DOT2(a0, Wz[4 * q + 0], aza); azb = DOT2(a1, Wz[4 * q + 1], azb);
        aza = DOT2(a2, Wz[4 * q + 2], aza); azb = DOT2(a3, Wz[4 * q + 3], azb);
        ana = DOT2(a0, Wn[4 * q + 0], ana); anb = DOT2(a1, Wn[4 * q + 1], anb);
        ana = DOT2(a2, Wn[4 * q + 2], ana); anb = DOT2(a3, Wn[4 * q + 3], anb);
      }
      float ar = ara + arb, az = aza + azb, an = ana + anb;
      float r = __builtin_amdgcn_rcpf(1.f + __expf(-ar));
      float z = __builtin_amdgcn_rcpf(1.f + __expf(-az));
      float pre = x2 + r * (an + bhn_r);
      float n = 1.f - 2.f * __builtin_amdgcn_rcpf(1.f + __expf(2.f * pre));  // tanh
      float hn = (1.f - z) * n + z * h;
      // -------- broadcast h_new; logits via register W_out rows --------
      if ((lane & 1) == 0) sh2[lane >> 1] = pack_pair(hn);
      float la_a = bo_r, la_b = 0.f;
      #pragma unroll
      for (int q = 0; q < 8; ++q) {
        uint4 hv = shv[q];
        la_a = DOT2(__builtin_bit_cast(h2, hv.x), Wo[4 * q + 0], la_a);
        la_b = DOT2(__builtin_bit_cast(h2, hv.y), Wo[4 * q + 1], la_b);
        la_a = DOT2(__builtin_bit_cast(h2, hv.z), Wo[4 * q + 2], la_a);
        la_b = DOT2(__builtin_bit_cast(h2, hv.w), Wo[4 * q + 3], la_b);
      }
      float logit = la_a + la_b;
      // -------- softmax without max pass (|logit| small by construction) --------
      if (lane < 18) sloge[lane] = __expf(logit);
      float4 e0 = *(const float4*)&sloge[0];
      float4 e1 = *(const float4*)&sloge[4];
      float4 e2 = *(const float4*)&sloge[8];
      float4 e3 = *(const float4*)&sloge[12];
      float4 e4 = *(const float4*)&sloge[16];    // [18],[19] are 0
      float ssum = (((e0.x + e0.y) + (e0.z + e0.w)) + ((e1.x + e1.y) + (e1.z + e1.w)))
                 + (((e2.x + e2.y) + (e2.z + e2.w)) + ((e3.x + e3.y) + (e3.z + e3.w)))
                 + ((e4.x + e4.y) + (e4.z + e4.w));
      float la = __builtin_bit_cast(float, __builtin_amdgcn_readlane(__builtin_bit_cast(int, logit), act));
      float lse = __logf(ssum);
      if (lane == 0) atomicAdd(&out[1 + s * 64 + b], lse - la);
      if (d > 0.f || u == 127) break;            // mask is 0 for all later steps
      // -------- advance --------
      u = un; x0 = nx0; x1 = nx1; x2 = nx2; d = nd; act = na;
      if (nd > 0.f) {
        h = nh;                                  // episode reset at next step start
        if ((lane & 1) == 0) sh2[lane >> 1] = pack_pair(h);
      } else {
        h = hn;                                  // sh2 already holds hn
      }
    }
  }
}

extern "C" void kernel_launch(void* const* d_in, const int* in_sizes, int n_in,
                              void* d_out, int out_size, void* d_ws, size_t ws_size,
                              hipStream_t stream) {
  const float* state = (const float*)d_in[0];
  const float* lm    = (const float*)d_in[1];
  const float* lv    = (const float*)d_in[2];
  const float* lmt   = (const float*)d_in[3];
  const float* lvt   = (const float*)d_in[4];
  const float* ac    = (const float*)d_in[5];
  const float* ms    = (const float*)d_in[6];
  const int*   actions = (const int*)d_in[7];
  const float* dones = (const float*)d_in[8];
  const float* Wst = (const float*)d_in[9],  *bst = (const float*)d_in[10];
  const float* Wac = (const float*)d_in[11], *bac = (const float*)d_in[12];
  const float* Wem = (const float*)d_in[13], *bem = (const float*)d_in[14];
  const float* Whd = (const float*)d_in[15], *bhd = (const float*)d_in[16];
  const float* Wi  = (const float*)d_in[17], *bi  = (const float*)d_in[18];
  const float* Whrz = (const float*)d_in[19];
  const float* Whn  = (const float*)d_in[20], *bhn = (const float*)d_in[21];
  const float* Wout = (const float*)d_in[22], *bout = (const float*)d_in[23];
  float* out = (float*)d_out;
  float* xi   = (float*)((char*)d_ws + XI_OFF);
  float* hid0 = (float*)((char*)d_ws + HID_OFF);
  unsigned int* ctr = (unsigned int*)((char*)d_ws + CTR_OFF);

  hipMemsetAsync(d_out, 0, (size_t)out_size * sizeof(float), stream);
  hipMemsetAsync(ctr, 0, sizeof(unsigned int), stream);

  hipLaunchKernelGGL(precompute_kernel, dim3(320), dim3(256), 0, stream,
                     state, ac, ms, Wst, bst, Wac, bac, Wem, bem, Whd, bhd, Wi, bi,
                     lm, lv, lmt, lvt, xi, hid0, out);
  hipLaunchKernelGGL(rollout_kernel, dim3(2048), dim3(64), 0, stream,
                     xi, hid0, dones, actions, Whrz, Whn, bhn, Wout, bout, out, ctr);
}